// Round 7
// baseline (349.904 us; speedup 1.0000x reference)
//
#include <hip/hip_runtime.h>
#include <hip/hip_bf16.h>

// Problem constants (fixed by the reference)
#define VOCAB 50000
#define D     300
#define B_    64
#define LC    32
#define T_    256
#define LT    64
#define NSEL  5

// A-image geometry: 32 rows x 40 slots (16B = 8 f16), k padded 300->320,
// slot s stored at s ^ (m&7) -> conflict-free ds_read_b128.
// hi: uint4[0..1280), lo: uint4[1280..2560). 40960 B per batch.
#define A_U4   2560
#define A_HALF 20480
#define TROW   320            // padded f16 row length in hi/lo tables

typedef _Float16 half8_t __attribute__((ext_vector_type(8)));
typedef float    f32x4   __attribute__((ext_vector_type(4)));

// ---------------- K0: whole-table f16 hi/lo conversion (fast path) -----------
__global__ __launch_bounds__(256) void k_prep_table(const float* __restrict__ emb,
                                                    _Float16* __restrict__ tabHi,
                                                    _Float16* __restrict__ tabLo) {
    int r = blockIdx.x * 4 + (threadIdx.x >> 6);     // 12500*4 = 50000 rows
    int lane = threadIdx.x & 63;
    const float* src = emb + (size_t)r * D;
    _Float16* dh = tabHi + (size_t)r * TROW;
    _Float16* dl = tabLo + (size_t)r * TROW;
#pragma unroll
    for (int i = 0; i < 5; ++i) {
        int k = lane + i * 64;
        float x = (k < D) ? src[k] : 0.0f;
        _Float16 h = (_Float16)x;
        dh[k] = h;
        dl[k] = (_Float16)(x - (float)h);
    }
}

// ---------------- K1: claim -> f16 hi/lo swizzled image in ws ----------------
__global__ void k_prep_claim(const int* __restrict__ claim,
                             const float* __restrict__ emb,
                             _Float16* __restrict__ wsA) {
    int row = blockIdx.x;                 // 0..B_*LC-1
    int b = row >> 5, m = row & 31;
    int tok = claim[row];
    const float* src = emb + (size_t)tok * D;
    _Float16* base = wsA + (size_t)b * A_HALF;
    for (int k = threadIdx.x; k < 320; k += 64) {
        float x = (k < D) ? src[k] : 0.0f;
        _Float16 h = (_Float16)x;
        float r = x - (float)h;
        _Float16 l = (_Float16)r;
        int sp = ((k >> 3) ^ (m & 7));
        int idx = (m * 40 + sp) * 8 + (k & 7);
        base[idx] = h;
        base[10240 + idx] = l;
    }
}

// hi/lo split of a float4 pair into half8 hi and half8 lo (slow path only)
__device__ __forceinline__ void split8(const float4& a, const float4& b,
                                       half8_t& hv, half8_t& lv) {
    float x[8] = {a.x, a.y, a.z, a.w, b.x, b.y, b.z, b.w};
#pragma unroll
    for (int i = 0; i < 8; ++i) {
        _Float16 h = (_Float16)x[i];
        hv[i] = h;
        lv[i] = (_Float16)(x[i] - (float)h);
    }
}

// ---------------- shared K-loop: U tile via f16x2-split MFMA ------------------
// Wave owns one t. acc[mi][ni] = 16x16 tile (c = mi*16+quad*4+reg, l = ni*16+ln).
template<bool FAST>
__device__ __forceinline__ void compute_U(const uint4* sA,
                                          const float* __restrict__ emb,
                                          const _Float16* __restrict__ tabHi,
                                          const _Float16* __restrict__ tabLo,
                                          const int* __restrict__ trow,
                                          int lane, f32x4 acc[2][4]) {
    int ln = lane & 15, quad = lane >> 4;
#pragma unroll
    for (int mi = 0; mi < 2; ++mi)
#pragma unroll
        for (int ni = 0; ni < 4; ++ni) acc[mi][ni] = (f32x4)0.0f;

    int arow0 = ln * 40;            // m = ln      (mi=0)
    int arow1 = (16 + ln) * 40;     // m = 16+ln   (mi=1)
    int key = ln & 7;

    if (FAST) {
        const _Float16* hp[4];
        const _Float16* lp[4];
#pragma unroll
        for (int ni = 0; ni < 4; ++ni) {
            int tok = trow[ni * 16 + ln];
            hp[ni] = tabHi + (size_t)tok * TROW;
            lp[ni] = tabLo + (size_t)tok * TROW;
        }
#pragma unroll 2
        for (int ks = 0; ks < 10; ++ks) {
            int ko = ks * 32 + quad * 8;      // this lane's 8 frag k's, 16B aligned
            half8_t bh[4], bl[4];
#pragma unroll
            for (int ni = 0; ni < 4; ++ni) {
                bh[ni] = *(const half8_t*)(hp[ni] + ko);
                bl[ni] = *(const half8_t*)(lp[ni] + ko);
            }
            int sp = (ks * 4 + quad) ^ key;
            half8_t ah[2], al[2];
            ah[0] = __builtin_bit_cast(half8_t, sA[arow0 + sp]);
            al[0] = __builtin_bit_cast(half8_t, sA[1280 + arow0 + sp]);
            ah[1] = __builtin_bit_cast(half8_t, sA[arow1 + sp]);
            al[1] = __builtin_bit_cast(half8_t, sA[1280 + arow1 + sp]);
#pragma unroll
            for (int mi = 0; mi < 2; ++mi)
#pragma unroll
                for (int ni = 0; ni < 4; ++ni) {
                    acc[mi][ni] = __builtin_amdgcn_mfma_f32_16x16x32_f16(ah[mi], bh[ni], acc[mi][ni], 0, 0, 0);
                    acc[mi][ni] = __builtin_amdgcn_mfma_f32_16x16x32_f16(ah[mi], bl[ni], acc[mi][ni], 0, 0, 0);
                    acc[mi][ni] = __builtin_amdgcn_mfma_f32_16x16x32_f16(al[mi], bh[ni], acc[mi][ni], 0, 0, 0);
                }
        }
    } else {
        const float* bp[4];
#pragma unroll
        for (int ni = 0; ni < 4; ++ni) {
            int tok = trow[ni * 16 + ln];
            bp[ni] = emb + (size_t)tok * D;
        }
#pragma unroll 1
        for (int ks = 0; ks < 10; ++ks) {
            int kb = ks * 32 + quad * 8;
            int ka = kb > 296 ? 296 : kb;
            int kb4 = kb + 4;
            int kbb = kb4 > 296 ? 296 : kb4;
            float4 b0[4], b1[4];
#pragma unroll
            for (int ni = 0; ni < 4; ++ni) {
                b0[ni] = *(const float4*)(bp[ni] + ka);
                b1[ni] = *(const float4*)(bp[ni] + kbb);
            }
            if (kb >= 296) {
                float4 z = make_float4(0.f, 0.f, 0.f, 0.f);
#pragma unroll
                for (int ni = 0; ni < 4; ++ni) {
                    if (kb >= 300) b0[ni] = z;
                    b1[ni] = z;
                }
            }
            int sp = (ks * 4 + quad) ^ key;
            half8_t ah[2], al[2];
            ah[0] = __builtin_bit_cast(half8_t, sA[arow0 + sp]);
            al[0] = __builtin_bit_cast(half8_t, sA[1280 + arow0 + sp]);
            ah[1] = __builtin_bit_cast(half8_t, sA[arow1 + sp]);
            al[1] = __builtin_bit_cast(half8_t, sA[1280 + arow1 + sp]);
            half8_t bh[4], bl[4];
#pragma unroll
            for (int ni = 0; ni < 4; ++ni) split8(b0[ni], b1[ni], bh[ni], bl[ni]);
#pragma unroll
            for (int mi = 0; mi < 2; ++mi)
#pragma unroll
                for (int ni = 0; ni < 4; ++ni) {
                    acc[mi][ni] = __builtin_amdgcn_mfma_f32_16x16x32_f16(ah[mi], bh[ni], acc[mi][ni], 0, 0, 0);
                    acc[mi][ni] = __builtin_amdgcn_mfma_f32_16x16x32_f16(ah[mi], bl[ni], acc[mi][ni], 0, 0, 0);
                    acc[mi][ni] = __builtin_amdgcn_mfma_f32_16x16x32_f16(al[mi], bh[ni], acc[mi][ni], 0, 0, 0);
                }
        }
    }
}

__device__ __forceinline__ float xmax4(float v) {
    v = fmaxf(v, __shfl_xor(v, 1)); v = fmaxf(v, __shfl_xor(v, 2));
    v = fmaxf(v, __shfl_xor(v, 4)); v = fmaxf(v, __shfl_xor(v, 8));
    return v;
}
__device__ __forceinline__ float xsum4(float v) {
    v += __shfl_xor(v, 1); v += __shfl_xor(v, 2);
    v += __shfl_xor(v, 4); v += __shfl_xor(v, 8);
    return v;
}

// ---------------- K2: target scores (wave-per-t, barrier-free K-loop) --------
template<bool FAST>
__global__ __launch_bounds__(256, 3) void k_scores(const int* __restrict__ targets,
                                                   const float* __restrict__ emb,
                                                   const _Float16* __restrict__ tabHi,
                                                   const _Float16* __restrict__ tabLo,
                                                   const _Float16* __restrict__ wsA,
                                                   float* __restrict__ wsScr) {
    __shared__ __align__(16) uint4 sA[A_U4];   // 40960 B
    int b = blockIdx.y, tid = threadIdx.x;
    {
        const uint4* src = (const uint4*)(wsA + (size_t)b * A_HALF);
        for (int i = tid; i < A_U4; i += 256) sA[i] = src[i];
    }
    __syncthreads();

    int lane = tid & 63, wave = tid >> 6;
    int t = blockIdx.x * 4 + wave;
    const int* trow = targets + ((size_t)b * T_ + t) * LT;

    f32x4 acc[2][4];
    compute_U<FAST>(sA, emb, tabHi, tabLo, trow, lane, acc);

    // softmax over l per c, max over c, sum over l — all in-wave
    float score_l[4] = {0.f, 0.f, 0.f, 0.f};
#pragma unroll
    for (int mi = 0; mi < 2; ++mi)
#pragma unroll
        for (int r = 0; r < 4; ++r) {
            float m = fmaxf(fmaxf(acc[mi][0][r], acc[mi][1][r]),
                            fmaxf(acc[mi][2][r], acc[mi][3][r]));
            m = xmax4(m);                     // max over 64 l for this c
            float p[4], s = 0.f;
#pragma unroll
            for (int ni = 0; ni < 4; ++ni) { p[ni] = __expf(acc[mi][ni][r] - m); s += p[ni]; }
            s = xsum4(s);                     // denom over 64 l
            float rv = 1.0f / s;
#pragma unroll
            for (int ni = 0; ni < 4; ++ni) score_l[ni] = fmaxf(score_l[ni], p[ni] * rv);
        }
    float tot = 0.f;
#pragma unroll
    for (int ni = 0; ni < 4; ++ni) {
        float v = score_l[ni];                // fold max over c across quads
        v = fmaxf(v, __shfl_xor(v, 16));
        v = fmaxf(v, __shfl_xor(v, 32));
        tot += v;
    }
    tot = xsum4(tot);                         // sum over the 16 ln-columns
    if (lane == 0) wsScr[b * T_ + t] = tot;
}

// ---------------- K3: top-5 per batch (descending, lowest-index ties) --------
__global__ void k_topn(const float* __restrict__ wsScr, int* __restrict__ wsIdx) {
    int b = blockIdx.x;
    int tid = threadIdx.x;              // 64 threads = 1 wave
    float v[4];
    for (int i = 0; i < 4; ++i) v[i] = wsScr[b * T_ + tid + 64 * i];
    for (int r = 0; r < NSEL; ++r) {
        float bv = v[0]; int bi = tid;
        for (int i = 1; i < 4; ++i) {
            int idx = tid + 64 * i;
            if (v[i] > bv) { bv = v[i]; bi = idx; }
        }
        for (int off = 32; off > 0; off >>= 1) {
            float ov = __shfl_down(bv, off);
            int   oi = __shfl_down(bi, off);
            if (ov > bv || (ov == bv && oi < bi)) { bv = ov; bi = oi; }
        }
        bi = __shfl(bi, 0);
        if (tid == 0) wsIdx[b * NSEL + r] = bi;
        if ((bi & 63) == tid) v[bi >> 6] = -1e30f;   // remove winner
    }
}

// ---------------- K4: recompute selected tiles, L2-normalize rows ------------
// One block per b; claim image staged once; wave w handles tiles j=w, w+4.
template<bool FAST>
__global__ __launch_bounds__(256) void k_output(const int* __restrict__ targets,
                                                const float* __restrict__ emb,
                                                const _Float16* __restrict__ tabHi,
                                                const _Float16* __restrict__ tabLo,
                                                const _Float16* __restrict__ wsA,
                                                const int* __restrict__ wsIdx,
                                                float* __restrict__ out) {
    __shared__ __align__(16) uint4 sA[A_U4];
    int b = blockIdx.x, tid = threadIdx.x;
    {
        const uint4* src = (const uint4*)(wsA + (size_t)b * A_HALF);
        for (int i = tid; i < A_U4; i += 256) sA[i] = src[i];
    }
    __syncthreads();

    int lane = tid & 63, wave = tid >> 6;
    int ln = lane & 15, quad = lane >> 4;

    for (int j = wave; j < NSEL; j += 4) {
        int t = wsIdx[b * NSEL + j];
        const int* trow = targets + ((size_t)b * T_ + t) * LT;
        f32x4 acc[2][4];
        compute_U<FAST>(sA, emb, tabHi, tabLo, trow, lane, acc);

        float* obase = out + (size_t)(b * NSEL + j) * (LC * LT);
#pragma unroll
        for (int mi = 0; mi < 2; ++mi)
#pragma unroll
            for (int r = 0; r < 4; ++r) {
                float ss = 0.f;
#pragma unroll
                for (int ni = 0; ni < 4; ++ni) ss = fmaf(acc[mi][ni][r], acc[mi][ni][r], ss);
                ss = xsum4(ss);                          // sum over 64 l
                float rinv = 1.0f / sqrtf(ss);
                int c = mi * 16 + quad * 4 + r;
#pragma unroll
                for (int ni = 0; ni < 4; ++ni)
                    obase[c * LT + ni * 16 + ln] = acc[mi][ni][r] * rinv;
            }
    }
}

extern "C" void kernel_launch(void* const* d_in, const int* in_sizes, int n_in,
                              void* d_out, int out_size, void* d_ws, size_t ws_size,
                              hipStream_t stream) {
    const int*   claim   = (const int*)d_in[0];
    const int*   targets = (const int*)d_in[1];
    const float* emb     = (const float*)d_in[2];
    // d_in[3] is n (=5), compile-time NSEL

    const size_t tabBytes = (size_t)VOCAB * TROW * sizeof(_Float16);   // 32 MB
    const size_t restBytes = (size_t)B_ * A_HALF * sizeof(_Float16)
                           + (size_t)B_ * T_ * sizeof(float)
                           + (size_t)B_ * NSEL * sizeof(int) + 256;
    bool fast = ws_size >= 2 * tabBytes + restBytes;   // deterministic per run

    char* p = (char*)d_ws;
    _Float16* tabHi = nullptr;
    _Float16* tabLo = nullptr;
    if (fast) {
        tabHi = (_Float16*)p; p += tabBytes;
        tabLo = (_Float16*)p; p += tabBytes;
    }
    _Float16* wsA = (_Float16*)p; p += (size_t)B_ * A_HALF * sizeof(_Float16);
    float* wsScr = (float*)p;     p += (size_t)B_ * T_ * sizeof(float);
    int*   wsIdx = (int*)p;
    float* out   = (float*)d_out;

    if (fast)
        k_prep_table<<<dim3(VOCAB / 4), dim3(256), 0, stream>>>(emb, tabHi, tabLo);
    k_prep_claim<<<dim3(B_ * LC), dim3(64), 0, stream>>>(claim, emb, wsA);
    if (fast) {
        k_scores<true><<<dim3(T_ / 4, B_), dim3(256), 0, stream>>>(targets, emb, tabHi, tabLo, wsA, wsScr);
        k_topn<<<dim3(B_), dim3(64), 0, stream>>>(wsScr, wsIdx);
        k_output<true><<<dim3(B_), dim3(256), 0, stream>>>(targets, emb, tabHi, tabLo, wsA, wsIdx, out);
    } else {
        k_scores<false><<<dim3(T_ / 4, B_), dim3(256), 0, stream>>>(targets, emb, tabHi, tabLo, wsA, wsScr);
        k_topn<<<dim3(B_), dim3(64), 0, stream>>>(wsScr, wsIdx);
        k_output<false><<<dim3(B_), dim3(256), 0, stream>>>(targets, emb, tabHi, tabLo, wsA, wsIdx, out);
    }
}

// Round 8
// 314.733 us; speedup vs baseline: 1.1117x; 1.1117x over previous
//
#include <hip/hip_runtime.h>
#include <hip/hip_bf16.h>

// Problem constants (fixed by the reference)
#define VOCAB 50000
#define D     300
#define B_    64
#define LC    32
#define T_    256
#define LT    64
#define NSEL  5

// A-image geometry: 32 rows x 40 slots (16B = 8 f16), k padded 300->320,
// slot s stored at s ^ (m&7) -> conflict-free ds_read_b128.
// hi: uint4[0..1280), lo: uint4[1280..2560). 40960 B per batch.
#define A_U4   2560
#define A_HALF 20480
#define TROW   640            // interleaved row: hi [0,320) | lo [320,640) halfs

typedef _Float16 half8_t __attribute__((ext_vector_type(8)));
typedef float    f32x4   __attribute__((ext_vector_type(4)));

// ---------------- K0: whole-table f16 hi|lo interleaved conversion ----------
__global__ __launch_bounds__(256) void k_prep_table(const float* __restrict__ emb,
                                                    _Float16* __restrict__ tab) {
    int r = blockIdx.x * 4 + (threadIdx.x >> 6);     // 12500*4 = 50000 rows
    int lane = threadIdx.x & 63;
    const float* src = emb + (size_t)r * D;
    _Float16* d = tab + (size_t)r * TROW;
#pragma unroll
    for (int i = 0; i < 5; ++i) {
        int k = lane + i * 64;
        float x = (k < D) ? src[k] : 0.0f;
        _Float16 h = (_Float16)x;
        d[k] = h;
        d[320 + k] = (_Float16)(x - (float)h);
    }
}

// ---------------- K1: claim -> f16 hi/lo swizzled image in ws ----------------
__global__ void k_prep_claim(const int* __restrict__ claim,
                             const float* __restrict__ emb,
                             _Float16* __restrict__ wsA) {
    int row = blockIdx.x;                 // 0..B_*LC-1
    int b = row >> 5, m = row & 31;
    int tok = claim[row];
    const float* src = emb + (size_t)tok * D;
    _Float16* base = wsA + (size_t)b * A_HALF;
    for (int k = threadIdx.x; k < 320; k += 64) {
        float x = (k < D) ? src[k] : 0.0f;
        _Float16 h = (_Float16)x;
        float r = x - (float)h;
        _Float16 l = (_Float16)r;
        int sp = ((k >> 3) ^ (m & 7));
        int idx = (m * 40 + sp) * 8 + (k & 7);
        base[idx] = h;
        base[10240 + idx] = l;
    }
}

// hi/lo split of a float4 pair into half8 hi and half8 lo (slow path only)
__device__ __forceinline__ void split8(const float4& a, const float4& b,
                                       half8_t& hv, half8_t& lv) {
    float x[8] = {a.x, a.y, a.z, a.w, b.x, b.y, b.z, b.w};
#pragma unroll
    for (int i = 0; i < 8; ++i) {
        _Float16 h = (_Float16)x[i];
        hv[i] = h;
        lv[i] = (_Float16)(x[i] - (float)h);
    }
}

// ---------------- shared K-loop: U tile via f16x2-split MFMA ------------------
// Wave owns one t. acc[mi][ni] = 16x16 tile (c = mi*16+quad*4+reg, l = ni*16+ln).
template<bool FAST>
__device__ __forceinline__ void compute_U(const uint4* sA,
                                          const float* __restrict__ emb,
                                          const _Float16* __restrict__ tab,
                                          const int* __restrict__ trow,
                                          int lane, f32x4 acc[2][4]) {
    int ln = lane & 15, quad = lane >> 4;
#pragma unroll
    for (int mi = 0; mi < 2; ++mi)
#pragma unroll
        for (int ni = 0; ni < 4; ++ni) acc[mi][ni] = (f32x4)0.0f;

    int arow0 = ln * 40;            // m = ln      (mi=0)
    int arow1 = (16 + ln) * 40;     // m = 16+ln   (mi=1)
    int key = ln & 7;

    if (FAST) {
        const _Float16* rp[4];
#pragma unroll
        for (int ni = 0; ni < 4; ++ni) {
            int tok = trow[ni * 16 + ln];
            rp[ni] = tab + (size_t)tok * TROW;
        }
        int qo = quad * 8;
        // depth-2 pipeline: B fragments double-buffered, loads base+imm only
        half8_t bh[2][4], bl[2][4];
#pragma unroll
        for (int ni = 0; ni < 4; ++ni) {
            bh[0][ni] = *(const half8_t*)(rp[ni] + qo);
            bl[0][ni] = *(const half8_t*)(rp[ni] + 320 + qo);
        }
#pragma unroll
        for (int ks = 0; ks < 10; ++ks) {
            int cur = ks & 1, nxt = cur ^ 1;
            if (ks < 9) {
                int ko = (ks + 1) * 32 + qo;
#pragma unroll
                for (int ni = 0; ni < 4; ++ni) {
                    bh[nxt][ni] = *(const half8_t*)(rp[ni] + ko);
                    bl[nxt][ni] = *(const half8_t*)(rp[ni] + 320 + ko);
                }
            }
            int sp = (ks * 4 + quad) ^ key;
            half8_t ah[2], al[2];
            ah[0] = __builtin_bit_cast(half8_t, sA[arow0 + sp]);
            al[0] = __builtin_bit_cast(half8_t, sA[1280 + arow0 + sp]);
            ah[1] = __builtin_bit_cast(half8_t, sA[arow1 + sp]);
            al[1] = __builtin_bit_cast(half8_t, sA[1280 + arow1 + sp]);
#pragma unroll
            for (int mi = 0; mi < 2; ++mi)
#pragma unroll
                for (int ni = 0; ni < 4; ++ni) {
                    acc[mi][ni] = __builtin_amdgcn_mfma_f32_16x16x32_f16(ah[mi], bh[cur][ni], acc[mi][ni], 0, 0, 0);
                    acc[mi][ni] = __builtin_amdgcn_mfma_f32_16x16x32_f16(ah[mi], bl[cur][ni], acc[mi][ni], 0, 0, 0);
                    acc[mi][ni] = __builtin_amdgcn_mfma_f32_16x16x32_f16(al[mi], bh[cur][ni], acc[mi][ni], 0, 0, 0);
                }
        }
    } else {
        const float* bp[4];
#pragma unroll
        for (int ni = 0; ni < 4; ++ni) {
            int tok = trow[ni * 16 + ln];
            bp[ni] = emb + (size_t)tok * D;
        }
#pragma unroll 1
        for (int ks = 0; ks < 10; ++ks) {
            int kb = ks * 32 + quad * 8;
            int ka = kb > 296 ? 296 : kb;
            int kb4 = kb + 4;
            int kbb = kb4 > 296 ? 296 : kb4;
            float4 b0[4], b1[4];
#pragma unroll
            for (int ni = 0; ni < 4; ++ni) {
                b0[ni] = *(const float4*)(bp[ni] + ka);
                b1[ni] = *(const float4*)(bp[ni] + kbb);
            }
            if (kb >= 296) {
                float4 z = make_float4(0.f, 0.f, 0.f, 0.f);
#pragma unroll
                for (int ni = 0; ni < 4; ++ni) {
                    if (kb >= 300) b0[ni] = z;
                    b1[ni] = z;
                }
            }
            int sp = (ks * 4 + quad) ^ key;
            half8_t ah[2], al[2];
            ah[0] = __builtin_bit_cast(half8_t, sA[arow0 + sp]);
            al[0] = __builtin_bit_cast(half8_t, sA[1280 + arow0 + sp]);
            ah[1] = __builtin_bit_cast(half8_t, sA[arow1 + sp]);
            al[1] = __builtin_bit_cast(half8_t, sA[1280 + arow1 + sp]);
            half8_t bh[4], bl[4];
#pragma unroll
            for (int ni = 0; ni < 4; ++ni) split8(b0[ni], b1[ni], bh[ni], bl[ni]);
#pragma unroll
            for (int mi = 0; mi < 2; ++mi)
#pragma unroll
                for (int ni = 0; ni < 4; ++ni) {
                    acc[mi][ni] = __builtin_amdgcn_mfma_f32_16x16x32_f16(ah[mi], bh[ni], acc[mi][ni], 0, 0, 0);
                    acc[mi][ni] = __builtin_amdgcn_mfma_f32_16x16x32_f16(ah[mi], bl[ni], acc[mi][ni], 0, 0, 0);
                    acc[mi][ni] = __builtin_amdgcn_mfma_f32_16x16x32_f16(al[mi], bh[ni], acc[mi][ni], 0, 0, 0);
                }
        }
    }
}

__device__ __forceinline__ float xmax4(float v) {
    v = fmaxf(v, __shfl_xor(v, 1)); v = fmaxf(v, __shfl_xor(v, 2));
    v = fmaxf(v, __shfl_xor(v, 4)); v = fmaxf(v, __shfl_xor(v, 8));
    return v;
}
__device__ __forceinline__ float xsum4(float v) {
    v += __shfl_xor(v, 1); v += __shfl_xor(v, 2);
    v += __shfl_xor(v, 4); v += __shfl_xor(v, 8);
    return v;
}

// ---------------- K2: target scores (wave-per-t, barrier-free K-loop) --------
template<bool FAST>
__global__ __launch_bounds__(256, 4) void k_scores(const int* __restrict__ targets,
                                                   const float* __restrict__ emb,
                                                   const _Float16* __restrict__ tab,
                                                   const _Float16* __restrict__ wsA,
                                                   float* __restrict__ wsScr) {
    __shared__ __align__(16) uint4 sA[A_U4];   // 40960 B -> 4 blocks/CU
    int b = blockIdx.y, tid = threadIdx.x;
    {
        const uint4* src = (const uint4*)(wsA + (size_t)b * A_HALF);
        for (int i = tid; i < A_U4; i += 256) sA[i] = src[i];
    }
    __syncthreads();

    int lane = tid & 63, wave = tid >> 6;
    int t = blockIdx.x * 4 + wave;
    const int* trow = targets + ((size_t)b * T_ + t) * LT;

    f32x4 acc[2][4];
    compute_U<FAST>(sA, emb, tab, trow, lane, acc);

    // softmax over l per c, max over c, sum over l — all in-wave
    float score_l[4] = {0.f, 0.f, 0.f, 0.f};
#pragma unroll
    for (int mi = 0; mi < 2; ++mi)
#pragma unroll
        for (int r = 0; r < 4; ++r) {
            float m = fmaxf(fmaxf(acc[mi][0][r], acc[mi][1][r]),
                            fmaxf(acc[mi][2][r], acc[mi][3][r]));
            m = xmax4(m);                     // max over 64 l for this c
            float p[4], s = 0.f;
#pragma unroll
            for (int ni = 0; ni < 4; ++ni) { p[ni] = __expf(acc[mi][ni][r] - m); s += p[ni]; }
            s = xsum4(s);                     // denom over 64 l
            float rv = 1.0f / s;
#pragma unroll
            for (int ni = 0; ni < 4; ++ni) score_l[ni] = fmaxf(score_l[ni], p[ni] * rv);
        }
    float tot = 0.f;
#pragma unroll
    for (int ni = 0; ni < 4; ++ni) {
        float v = score_l[ni];                // fold max over c across quads
        v = fmaxf(v, __shfl_xor(v, 16));
        v = fmaxf(v, __shfl_xor(v, 32));
        tot += v;
    }
    tot = xsum4(tot);                         // sum over the 16 ln-columns
    if (lane == 0) wsScr[b * T_ + t] = tot;
}

// ---------------- K3: top-5 per batch (descending, lowest-index ties) --------
__global__ void k_topn(const float* __restrict__ wsScr, int* __restrict__ wsIdx) {
    int b = blockIdx.x;
    int tid = threadIdx.x;              // 64 threads = 1 wave
    float v[4];
    for (int i = 0; i < 4; ++i) v[i] = wsScr[b * T_ + tid + 64 * i];
    for (int r = 0; r < NSEL; ++r) {
        float bv = v[0]; int bi = tid;
        for (int i = 1; i < 4; ++i) {
            int idx = tid + 64 * i;
            if (v[i] > bv) { bv = v[i]; bi = idx; }
        }
        for (int off = 32; off > 0; off >>= 1) {
            float ov = __shfl_down(bv, off);
            int   oi = __shfl_down(bi, off);
            if (ov > bv || (ov == bv && oi < bi)) { bv = ov; bi = oi; }
        }
        bi = __shfl(bi, 0);
        if (tid == 0) wsIdx[b * NSEL + r] = bi;
        if ((bi & 63) == tid) v[bi >> 6] = -1e30f;   // remove winner
    }
}

// ---------------- K4: recompute selected tiles, L2-normalize rows ------------
// One block per b; claim image staged once; wave w handles tiles j=w, w+4.
template<bool FAST>
__global__ __launch_bounds__(256) void k_output(const int* __restrict__ targets,
                                                const float* __restrict__ emb,
                                                const _Float16* __restrict__ tab,
                                                const _Float16* __restrict__ wsA,
                                                const int* __restrict__ wsIdx,
                                                float* __restrict__ out) {
    __shared__ __align__(16) uint4 sA[A_U4];
    int b = blockIdx.x, tid = threadIdx.x;
    {
        const uint4* src = (const uint4*)(wsA + (size_t)b * A_HALF);
        for (int i = tid; i < A_U4; i += 256) sA[i] = src[i];
    }
    __syncthreads();

    int lane = tid & 63, wave = tid >> 6;
    int ln = lane & 15, quad = lane >> 4;

    for (int j = wave; j < NSEL; j += 4) {
        int t = wsIdx[b * NSEL + j];
        const int* trow = targets + ((size_t)b * T_ + t) * LT;
        f32x4 acc[2][4];
        compute_U<FAST>(sA, emb, tab, trow, lane, acc);

        float* obase = out + (size_t)(b * NSEL + j) * (LC * LT);
#pragma unroll
        for (int mi = 0; mi < 2; ++mi)
#pragma unroll
            for (int r = 0; r < 4; ++r) {
                float ss = 0.f;
#pragma unroll
                for (int ni = 0; ni < 4; ++ni) ss = fmaf(acc[mi][ni][r], acc[mi][ni][r], ss);
                ss = xsum4(ss);                          // sum over 64 l
                float rinv = 1.0f / sqrtf(ss);
                int c = mi * 16 + quad * 4 + r;
#pragma unroll
                for (int ni = 0; ni < 4; ++ni)
                    obase[c * LT + ni * 16 + ln] = acc[mi][ni][r] * rinv;
            }
    }
}

extern "C" void kernel_launch(void* const* d_in, const int* in_sizes, int n_in,
                              void* d_out, int out_size, void* d_ws, size_t ws_size,
                              hipStream_t stream) {
    const int*   claim   = (const int*)d_in[0];
    const int*   targets = (const int*)d_in[1];
    const float* emb     = (const float*)d_in[2];
    // d_in[3] is n (=5), compile-time NSEL

    const size_t tabBytes = (size_t)VOCAB * TROW * sizeof(_Float16);   // 64 MB
    const size_t restBytes = (size_t)B_ * A_HALF * sizeof(_Float16)
                           + (size_t)B_ * T_ * sizeof(float)
                           + (size_t)B_ * NSEL * sizeof(int) + 256;
    bool fast = ws_size >= tabBytes + restBytes;   // deterministic per run

    char* p = (char*)d_ws;
    _Float16* tab = nullptr;
    if (fast) { tab = (_Float16*)p; p += tabBytes; }
    _Float16* wsA = (_Float16*)p; p += (size_t)B_ * A_HALF * sizeof(_Float16);
    float* wsScr = (float*)p;     p += (size_t)B_ * T_ * sizeof(float);
    int*   wsIdx = (int*)p;
    float* out   = (float*)d_out;

    if (fast)
        k_prep_table<<<dim3(VOCAB / 4), dim3(256), 0, stream>>>(emb, tab);
    k_prep_claim<<<dim3(B_ * LC), dim3(64), 0, stream>>>(claim, emb, wsA);
    if (fast) {
        k_scores<true><<<dim3(T_ / 4, B_), dim3(256), 0, stream>>>(targets, emb, tab, wsA, wsScr);
        k_topn<<<dim3(B_), dim3(64), 0, stream>>>(wsScr, wsIdx);
        k_output<true><<<dim3(B_), dim3(256), 0, stream>>>(targets, emb, tab, wsA, wsIdx, out);
    } else {
        k_scores<false><<<dim3(T_ / 4, B_), dim3(256), 0, stream>>>(targets, emb, tab, wsA, wsScr);
        k_topn<<<dim3(B_), dim3(64), 0, stream>>>(wsScr, wsIdx);
        k_output<false><<<dim3(B_), dim3(256), 0, stream>>>(targets, emb, tab, wsA, wsIdx, out);
    }
}